// Round 1
// baseline (790.007 us; speedup 1.0000x reference)
//
#include <hip/hip_runtime.h>
#include <math.h>

#define B_   4
#define C_   256
#define H_   96
#define W_   96
#define HW_  (H_ * W_)
#define G_   4
#define CG_  64
#define K_   9

// ---------------------------------------------------------------------------
// prep: transpose weights for fast access.
//  owt[(c*9+tap)*24 + j]  = offset_w[j][c][tap]      (18*2304 -> padded stride 24)
//  wt2[((g*9+k)*64+c)*64+co] = weight[(g*64+co)][c][k]
// ---------------------------------------------------------------------------
__global__ __launch_bounds__(256) void prep_kernel(
    const float* __restrict__ ow, const float* __restrict__ wt,
    float* __restrict__ owt, float* __restrict__ wt2)
{
    int idx = blockIdx.x * 256 + threadIdx.x;
    if (idx < 18 * 2304) {
        int j = idx / 2304;
        int r = idx - j * 2304;           // r = c*9 + tap
        owt[r * 24 + j] = ow[idx];
    }
    if (idx < G_ * K_ * CG_ * CG_) {      // 147456
        int co   = idx & 63;
        int rest = idx >> 6;              // (g*9+k)*64 + c
        int c    = rest & 63;
        int gk   = rest >> 6;             // g*9 + k
        int g    = gk / 9;
        int kk   = gk - g * 9;
        wt2[idx] = wt[(((g * CG_ + co) * CG_ + c) * 9) + kk];
    }
}

// ---------------------------------------------------------------------------
// offset conv: off[b][j][h][w] = sum_{c,tap} x[b][c][h+ky-1][w+kx-1]*W + bias
// grid 288 blocks x 512 threads: 128 spatial positions x 4 channel-chunks(64)
// ---------------------------------------------------------------------------
__global__ __launch_bounds__(512) void offset_conv_kernel(
    const float* __restrict__ x, const float* __restrict__ owt,
    const float* __restrict__ bias, float* __restrict__ off)
{
    int blk   = blockIdx.x;               // 0..287
    int b     = blk / 72;
    int sp    = (blk % 72) * 128 + (threadIdx.x & 127);
    int chunk = threadIdx.x >> 7;         // 0..3  (wave-uniform)
    int h     = sp / W_;
    int w     = sp - h * W_;

    float acc[18];
#pragma unroll
    for (int j = 0; j < 18; ++j) acc[j] = 0.f;

    const float* xb = x + b * (C_ * HW_);
    int c0 = chunk * 64;
    for (int c = c0; c < c0 + 64; ++c) {
        const float* xc = xb + c * HW_;
        const float* wr = owt + (c * 9) * 24;
#pragma unroll
        for (int ky = 0; ky < 3; ++ky) {
            int y = h + ky - 1;
#pragma unroll
            for (int kx = 0; kx < 3; ++kx) {
                int xx = w + kx - 1;
                float v = 0.f;
                if ((unsigned)y < H_ && (unsigned)xx < W_) v = xc[y * W_ + xx];
                const float* wtap = wr + (ky * 3 + kx) * 24;
                float4 w0 = *(const float4*)(wtap + 0);
                float4 w1 = *(const float4*)(wtap + 4);
                float4 w2 = *(const float4*)(wtap + 8);
                float4 w3 = *(const float4*)(wtap + 12);
                float2 w4 = *(const float2*)(wtap + 16);
                acc[0]  = fmaf(v, w0.x, acc[0]);
                acc[1]  = fmaf(v, w0.y, acc[1]);
                acc[2]  = fmaf(v, w0.z, acc[2]);
                acc[3]  = fmaf(v, w0.w, acc[3]);
                acc[4]  = fmaf(v, w1.x, acc[4]);
                acc[5]  = fmaf(v, w1.y, acc[5]);
                acc[6]  = fmaf(v, w1.z, acc[6]);
                acc[7]  = fmaf(v, w1.w, acc[7]);
                acc[8]  = fmaf(v, w2.x, acc[8]);
                acc[9]  = fmaf(v, w2.y, acc[9]);
                acc[10] = fmaf(v, w2.z, acc[10]);
                acc[11] = fmaf(v, w2.w, acc[11]);
                acc[12] = fmaf(v, w3.x, acc[12]);
                acc[13] = fmaf(v, w3.y, acc[13]);
                acc[14] = fmaf(v, w3.z, acc[14]);
                acc[15] = fmaf(v, w3.w, acc[15]);
                acc[16] = fmaf(v, w4.x, acc[16]);
                acc[17] = fmaf(v, w4.y, acc[17]);
            }
        }
    }
    // 4-way chunk reduction in LDS (stride 19 to dodge bank conflicts)
    __shared__ float red[512 * 19];
#pragma unroll
    for (int j = 0; j < 18; ++j) red[threadIdx.x * 19 + j] = acc[j];
    __syncthreads();
    if (chunk == 0) {
        int sl = threadIdx.x;             // 0..127
#pragma unroll
        for (int j = 0; j < 18; ++j) {
            float s = red[sl * 19 + j] + red[(sl + 128) * 19 + j]
                    + red[(sl + 256) * 19 + j] + red[(sl + 384) * 19 + j];
            off[b * (18 * HW_) + j * HW_ + sp] = s + bias[j];
        }
    }
}

// ---------------------------------------------------------------------------
// deform conv + grouped matmul, fused.
// grid B*G*H = 1536 blocks x 256 threads. Block owns out[b][g*64..+64][h][:]
// Per k-tap: stage W_k[c][co] (16KB) + sampled S_k[c][w] (24KB) in LDS,
// then 4co x 6w register-tiled outer product over c=0..63.
// ---------------------------------------------------------------------------
__global__ __launch_bounds__(256) void deform_kernel(
    const float* __restrict__ x, const float* __restrict__ off,
    const float* __restrict__ wt2, float* __restrict__ out)
{
    int blk = blockIdx.x;                 // B*G*H
    int h   = blk % H_;
    int bg  = blk / H_;
    int g   = bg % G_;
    int b   = bg / G_;
    int t   = threadIdx.x;

    __shared__ __align__(16) float sW[CG_ * CG_];   // [c][co]
    __shared__ __align__(16) float sS[CG_ * W_];    // [c][w]
    __shared__ float sww[4][W_];                    // masked bilinear weights
    __shared__ int   sof[4][W_];                    // clamped corner offsets

    const float* xp   = x + (b * C_ + g * CG_) * HW_;
    const float* offb = off + b * (18 * HW_) + h * W_;

    int tco = t & 15;                     // -> co = tco*4
    int tw  = t >> 4;                     // -> w  = tw*6

    float acc[4][6];
#pragma unroll
    for (int i = 0; i < 4; ++i)
#pragma unroll
        for (int j = 0; j < 6; ++j) acc[i][j] = 0.f;

    for (int k = 0; k < K_; ++k) {
        __syncthreads();                  // protect LDS reuse across taps
        // stage W_k (coalesced from pre-transposed wt2)
        const float* wsrc = wt2 + (g * 9 + k) * (CG_ * CG_);
#pragma unroll
        for (int i = 0; i < 16; ++i) sW[t + i * 256] = wsrc[t + i * 256];

        // per-(k,w) sampling table: 4 masked weights + 4 clamped offsets
        if (t < W_) {
            int w  = t;
            int ky = k / 3, kx = k - ky * 3;
            float dy = offb[(2 * k) * HW_ + w];
            float dx = offb[(2 * k + 1) * HW_ + w];
            float py = (float)(h + ky - 1) + dy;
            float px = (float)(w + kx - 1) + dx;
            bool valid = (py > -1.f) && (py < (float)H_) &&
                         (px > -1.f) && (px < (float)W_);
            float y0f = floorf(py), x0f = floorf(px);
            float ly = py - y0f, lx = px - x0f;
            int y0 = (int)y0f, x0 = (int)x0f;
            int y1 = y0 + 1,  x1 = x0 + 1;
            bool y0ok = valid && (y0 >= 0) && (y0 < H_);
            bool y1ok = valid && (y1 >= 0) && (y1 < H_);
            bool x0ok = (x0 >= 0) && (x0 < W_);
            bool x1ok = (x1 >= 0) && (x1 < W_);
            int y0c = min(max(y0, 0), H_ - 1) * W_;
            int y1c = min(max(y1, 0), H_ - 1) * W_;
            int x0c = min(max(x0, 0), W_ - 1);
            int x1c = min(max(x1, 0), W_ - 1);
            sww[0][w] = (y0ok && x0ok) ? (1.f - ly) * (1.f - lx) : 0.f;
            sww[1][w] = (y0ok && x1ok) ? (1.f - ly) * lx : 0.f;
            sww[2][w] = (y1ok && x0ok) ? ly * (1.f - lx) : 0.f;
            sww[3][w] = (y1ok && x1ok) ? ly * lx : 0.f;
            sof[0][w] = y0c + x0c;
            sof[1][w] = y0c + x1c;
            sof[2][w] = y1c + x0c;
            sof[3][w] = y1c + x1c;
        }
        __syncthreads();

        // stage S_k: 64c x 96w bilinear samples (weights shared across c)
#pragma unroll
        for (int i = 0; i < 24; ++i) {
            int idx = t + i * 256;        // 0..6143
            int c = idx / W_;
            int w = idx - c * W_;
            const float* xc = xp + c * HW_;
            float v = sww[0][w] * xc[sof[0][w]]
                    + sww[1][w] * xc[sof[1][w]]
                    + sww[2][w] * xc[sof[2][w]]
                    + sww[3][w] * xc[sof[3][w]];
            sS[c * W_ + w] = v;
        }
        __syncthreads();

        // matmul accumulate: acc[4co][6w] += W_k^T * S_k
        const float* sWp = sW + tco * 4;
        const float* sSp = sS + tw * 6;
#pragma unroll 4
        for (int c = 0; c < CG_; ++c) {
            float4 wv  = *(const float4*)(sWp + c * CG_);
            float2 s01 = *(const float2*)(sSp + c * W_ + 0);
            float2 s23 = *(const float2*)(sSp + c * W_ + 2);
            float2 s45 = *(const float2*)(sSp + c * W_ + 4);
            float wa[4] = {wv.x, wv.y, wv.z, wv.w};
            float sv[6] = {s01.x, s01.y, s23.x, s23.y, s45.x, s45.y};
#pragma unroll
            for (int i = 0; i < 4; ++i)
#pragma unroll
                for (int j = 0; j < 6; ++j)
                    acc[i][j] = fmaf(wa[i], sv[j], acc[i][j]);
        }
    }

    float* ob = out + (b * C_ + g * CG_ + tco * 4) * HW_ + h * W_ + tw * 6;
#pragma unroll
    for (int i = 0; i < 4; ++i)
#pragma unroll
        for (int j = 0; j < 6; ++j)
            ob[i * HW_ + j] = acc[i][j];
}

// ---------------------------------------------------------------------------
extern "C" void kernel_launch(void* const* d_in, const int* in_sizes, int n_in,
                              void* d_out, int out_size, void* d_ws, size_t ws_size,
                              hipStream_t stream) {
    const float* x    = (const float*)d_in[0];
    const float* ow   = (const float*)d_in[1];   // offset_w (18,256,3,3)
    const float* obi  = (const float*)d_in[2];   // offset_b (18,)
    const float* wt   = (const float*)d_in[3];   // weight   (256,64,3,3)

    // workspace layout (floats): offsets | owt (2304*24) | wt2 (147456)
    float* off = (float*)d_ws;                               // 663552 floats
    float* owt = off + (size_t)B_ * 18 * HW_;                // 55296 floats
    float* wt2 = owt + 2304 * 24;                            // 147456 floats

    prep_kernel<<<(G_ * K_ * CG_ * CG_ + 255) / 256, 256, 0, stream>>>(ow, wt, owt, wt2);
    offset_conv_kernel<<<288, 512, 0, stream>>>(x, owt, obi, off);
    deform_kernel<<<B_ * G_ * H_, 256, 0, stream>>>(x, off, wt2, (float*)d_out);
}

// Round 2
// 697.974 us; speedup vs baseline: 1.1319x; 1.1319x over previous
//
#include <hip/hip_runtime.h>
#include <math.h>

#define B_   4
#define C_   256
#define H_   96
#define W_   96
#define HW_  (H_ * W_)
#define G_   4
#define CG_  64
#define K_   9

// ---------------------------------------------------------------------------
// prep: transpose weights for fast access.
//  owt[(c*9+tap)*24 + j]  = offset_w[j][c][tap]      (18*2304 -> padded stride 24)
//  wt2[((g*9+k)*64+c)*64+co] = weight[(g*64+co)][c][k]
// ---------------------------------------------------------------------------
__global__ __launch_bounds__(256) void prep_kernel(
    const float* __restrict__ ow, const float* __restrict__ wt,
    float* __restrict__ owt, float* __restrict__ wt2)
{
    int idx = blockIdx.x * 256 + threadIdx.x;
    if (idx < 18 * 2304) {
        int j = idx / 2304;
        int r = idx - j * 2304;           // r = c*9 + tap
        owt[r * 24 + j] = ow[idx];
    }
    if (idx < G_ * K_ * CG_ * CG_) {      // 147456
        int co   = idx & 63;
        int rest = idx >> 6;              // (g*9+k)*64 + c
        int c    = rest & 63;
        int gk   = rest >> 6;             // g*9 + k
        int g    = gk / 9;
        int kk   = gk - g * 9;
        wt2[idx] = wt[(((g * CG_ + co) * CG_ + c) * 9) + kk];
    }
}

// ---------------------------------------------------------------------------
// offset conv: off[b][j][h][w] = sum_{c,tap} x[b][c][h+ky-1][w+kx-1]*W + bias
// grid 1152 blocks x 256 threads: 32 spatial positions x 8 channel-chunks(32)
// (8-way c-split doubles wave count vs r1: 18 waves/CU for latency hiding)
// ---------------------------------------------------------------------------
__global__ __launch_bounds__(256) void offset_conv_kernel(
    const float* __restrict__ x, const float* __restrict__ owt,
    const float* __restrict__ bias, float* __restrict__ off)
{
    int blk   = blockIdx.x;               // 0..1151
    int b     = blk / 288;
    int sp    = (blk % 288) * 32 + (threadIdx.x & 31);
    int chunk = threadIdx.x >> 5;         // 0..7
    int h     = sp / W_;
    int w     = sp - h * W_;

    float acc[18];
#pragma unroll
    for (int j = 0; j < 18; ++j) acc[j] = 0.f;

    const float* xb = x + b * (C_ * HW_);
    int c0 = chunk * 32;
#pragma unroll 2
    for (int c = c0; c < c0 + 32; ++c) {
        const float* xc = xb + c * HW_;
        const float* wr = owt + (c * 9) * 24;
        // 9 independent masked loads first (ILP for latency hiding)
        float v[9];
#pragma unroll
        for (int ky = 0; ky < 3; ++ky) {
            int y = h + ky - 1;
#pragma unroll
            for (int kx = 0; kx < 3; ++kx) {
                int xx = w + kx - 1;
                float t = 0.f;
                if ((unsigned)y < H_ && (unsigned)xx < W_) t = xc[y * W_ + xx];
                v[ky * 3 + kx] = t;
            }
        }
#pragma unroll
        for (int tap = 0; tap < 9; ++tap) {
            const float* wtap = wr + tap * 24;   // wave-uniform -> s_load
            float4 w0 = *(const float4*)(wtap + 0);
            float4 w1 = *(const float4*)(wtap + 4);
            float4 w2 = *(const float4*)(wtap + 8);
            float4 w3 = *(const float4*)(wtap + 12);
            float2 w4 = *(const float2*)(wtap + 16);
            float vv = v[tap];
            acc[0]  = fmaf(vv, w0.x, acc[0]);
            acc[1]  = fmaf(vv, w0.y, acc[1]);
            acc[2]  = fmaf(vv, w0.z, acc[2]);
            acc[3]  = fmaf(vv, w0.w, acc[3]);
            acc[4]  = fmaf(vv, w1.x, acc[4]);
            acc[5]  = fmaf(vv, w1.y, acc[5]);
            acc[6]  = fmaf(vv, w1.z, acc[6]);
            acc[7]  = fmaf(vv, w1.w, acc[7]);
            acc[8]  = fmaf(vv, w2.x, acc[8]);
            acc[9]  = fmaf(vv, w2.y, acc[9]);
            acc[10] = fmaf(vv, w2.z, acc[10]);
            acc[11] = fmaf(vv, w2.w, acc[11]);
            acc[12] = fmaf(vv, w3.x, acc[12]);
            acc[13] = fmaf(vv, w3.y, acc[13]);
            acc[14] = fmaf(vv, w3.z, acc[14]);
            acc[15] = fmaf(vv, w3.w, acc[15]);
            acc[16] = fmaf(vv, w4.x, acc[16]);
            acc[17] = fmaf(vv, w4.y, acc[17]);
        }
    }
    // 8-way chunk reduction in LDS (stride 19 to dodge bank conflicts)
    __shared__ float red[256 * 19];
#pragma unroll
    for (int j = 0; j < 18; ++j) red[threadIdx.x * 19 + j] = acc[j];
    __syncthreads();
    if (chunk == 0) {
        int sl = threadIdx.x;             // 0..31
#pragma unroll
        for (int j = 0; j < 18; ++j) {
            float s = 0.f;
#pragma unroll
            for (int kc = 0; kc < 8; ++kc) s += red[(sl + kc * 32) * 19 + j];
            off[b * (18 * HW_) + j * HW_ + sp] = s + bias[j];
        }
    }
}

// ---------------------------------------------------------------------------
// deform conv + grouped matmul, fused.
// grid B*G*H = 1536 blocks x 256 threads. Block owns out[b][g*64..+64][h][:]
// XCD swizzle: blocks are dispatched round-robin across 8 XCDs (blk % 8), so
// pin each XCD to 2 (b,g) slices (2.4 MB each) with h sequential -> the x
// slice stays resident in that XCD's 4 MB L2 across all 96 h-blocks.
// ---------------------------------------------------------------------------
__global__ __launch_bounds__(256) void deform_kernel(
    const float* __restrict__ x, const float* __restrict__ off,
    const float* __restrict__ wt2, float* __restrict__ out)
{
    int blk = blockIdx.x;                 // 0..1535
    int xcd = blk & 7;
    int s   = blk >> 3;                   // 0..191
    int bg  = xcd * 2 + (s / H_);         // 0..15
    int h   = s % H_;
    int g   = bg & 3;
    int b   = bg >> 2;
    int t   = threadIdx.x;

    __shared__ __align__(16) float sW[CG_ * CG_];   // [c][co]
    __shared__ __align__(16) float sS[CG_ * W_];    // [c][w]
    __shared__ float sww[4][W_];                    // masked bilinear weights
    __shared__ int   sof[4][W_];                    // clamped corner offsets

    const float* xp   = x + (b * C_ + g * CG_) * HW_;
    const float* offb = off + b * (18 * HW_) + h * W_;

    int tco = t & 15;                     // -> co = tco*4
    int tw  = t >> 4;                     // -> w  = tw*6

    float acc[4][6];
#pragma unroll
    for (int i = 0; i < 4; ++i)
#pragma unroll
        for (int j = 0; j < 6; ++j) acc[i][j] = 0.f;

    for (int k = 0; k < K_; ++k) {
        __syncthreads();                  // protect LDS reuse across taps
        // stage W_k (coalesced from pre-transposed wt2)
        const float* wsrc = wt2 + (g * 9 + k) * (CG_ * CG_);
#pragma unroll
        for (int i = 0; i < 16; ++i) sW[t + i * 256] = wsrc[t + i * 256];

        // per-(k,w) sampling table: 4 masked weights + 4 clamped offsets
        if (t < W_) {
            int w  = t;
            int ky = k / 3, kx = k - ky * 3;
            float dy = offb[(2 * k) * HW_ + w];
            float dx = offb[(2 * k + 1) * HW_ + w];
            float py = (float)(h + ky - 1) + dy;
            float px = (float)(w + kx - 1) + dx;
            bool valid = (py > -1.f) && (py < (float)H_) &&
                         (px > -1.f) && (px < (float)W_);
            float y0f = floorf(py), x0f = floorf(px);
            float ly = py - y0f, lx = px - x0f;
            int y0 = (int)y0f, x0 = (int)x0f;
            int y1 = y0 + 1,  x1 = x0 + 1;
            bool y0ok = valid && (y0 >= 0) && (y0 < H_);
            bool y1ok = valid && (y1 >= 0) && (y1 < H_);
            bool x0ok = (x0 >= 0) && (x0 < W_);
            bool x1ok = (x1 >= 0) && (x1 < W_);
            int y0c = min(max(y0, 0), H_ - 1) * W_;
            int y1c = min(max(y1, 0), H_ - 1) * W_;
            int x0c = min(max(x0, 0), W_ - 1);
            int x1c = min(max(x1, 0), W_ - 1);
            sww[0][w] = (y0ok && x0ok) ? (1.f - ly) * (1.f - lx) : 0.f;
            sww[1][w] = (y0ok && x1ok) ? (1.f - ly) * lx : 0.f;
            sww[2][w] = (y1ok && x0ok) ? ly * (1.f - lx) : 0.f;
            sww[3][w] = (y1ok && x1ok) ? ly * lx : 0.f;
            sof[0][w] = y0c + x0c;
            sof[1][w] = y0c + x1c;
            sof[2][w] = y1c + x0c;
            sof[3][w] = y1c + x1c;
        }
        __syncthreads();

        // stage S_k: 64c x 96w bilinear samples (weights shared across c)
#pragma unroll
        for (int i = 0; i < 24; ++i) {
            int idx = t + i * 256;        // 0..6143
            int c = idx / W_;
            int w = idx - c * W_;
            const float* xc = xp + c * HW_;
            float v = sww[0][w] * xc[sof[0][w]]
                    + sww[1][w] * xc[sof[1][w]]
                    + sww[2][w] * xc[sof[2][w]]
                    + sww[3][w] * xc[sof[3][w]];
            sS[c * W_ + w] = v;
        }
        __syncthreads();

        // matmul accumulate: acc[4co][6w] += W_k^T * S_k
        const float* sWp = sW + tco * 4;
        const float* sSp = sS + tw * 6;
#pragma unroll 4
        for (int c = 0; c < CG_; ++c) {
            float4 wv  = *(const float4*)(sWp + c * CG_);
            float2 s01 = *(const float2*)(sSp + c * W_ + 0);
            float2 s23 = *(const float2*)(sSp + c * W_ + 2);
            float2 s45 = *(const float2*)(sSp + c * W_ + 4);
            float wa[4] = {wv.x, wv.y, wv.z, wv.w};
            float sv[6] = {s01.x, s01.y, s23.x, s23.y, s45.x, s45.y};
#pragma unroll
            for (int i = 0; i < 4; ++i)
#pragma unroll
                for (int j = 0; j < 6; ++j)
                    acc[i][j] = fmaf(wa[i], sv[j], acc[i][j]);
        }
    }

    // non-temporal stores: keep the 37 MB of C out of L2 so the x slice
    // (2.4 MB per (b,g)) stays resident for the other 95 h-blocks.
    float* ob = out + (b * C_ + g * CG_ + tco * 4) * HW_ + h * W_ + tw * 6;
#pragma unroll
    for (int i = 0; i < 4; ++i)
#pragma unroll
        for (int j = 0; j < 6; ++j)
            __builtin_nontemporal_store(acc[i][j], ob + i * HW_ + j);
}

// ---------------------------------------------------------------------------
extern "C" void kernel_launch(void* const* d_in, const int* in_sizes, int n_in,
                              void* d_out, int out_size, void* d_ws, size_t ws_size,
                              hipStream_t stream) {
    const float* x    = (const float*)d_in[0];
    const float* ow   = (const float*)d_in[1];   // offset_w (18,256,3,3)
    const float* obi  = (const float*)d_in[2];   // offset_b (18,)
    const float* wt   = (const float*)d_in[3];   // weight   (256,64,3,3)

    // workspace layout (floats): offsets | owt (2304*24) | wt2 (147456)
    float* off = (float*)d_ws;                               // 663552 floats
    float* owt = off + (size_t)B_ * 18 * HW_;                // 55296 floats
    float* wt2 = owt + 2304 * 24;                            // 147456 floats

    prep_kernel<<<(G_ * K_ * CG_ * CG_ + 255) / 256, 256, 0, stream>>>(ow, wt, owt, wt2);
    offset_conv_kernel<<<1152, 256, 0, stream>>>(x, owt, obi, off);
    deform_kernel<<<B_ * G_ * H_, 256, 0, stream>>>(x, off, wt2, (float*)d_out);
}

// Round 3
// 489.043 us; speedup vs baseline: 1.6154x; 1.4272x over previous
//
#include <hip/hip_runtime.h>
#include <hip/hip_bf16.h>
#include <math.h>

#define B_   4
#define C_   256
#define H_   96
#define W_   96
#define HW_  (H_ * W_)
#define G_   4
#define CG_  64
#define K_   9

typedef __bf16  bf16x8 __attribute__((ext_vector_type(8)));
typedef float   f32x4  __attribute__((ext_vector_type(4)));

// ---------------------------------------------------------------------------
// prep:
//  owt[(c*9+tap)*24 + j] = offset_w[j][c][tap]   (fp32, padded stride 24)
//  aW: deform weights as bf16 in MFMA A-fragment lane order:
//    idx = ((((g*9+tap)*2+ks)*2+half)*2+ct)*512 + lane*8 + j
//    c  = ks*32 + (lane>>4)*8 + j ;  co = half*32 + ct*16 + (lane&15)
// ---------------------------------------------------------------------------
__global__ __launch_bounds__(256) void prep_kernel(
    const float* __restrict__ ow, const float* __restrict__ wt,
    float* __restrict__ owt, __hip_bfloat16* __restrict__ aW)
{
    int idx = blockIdx.x * 256 + threadIdx.x;
    if (idx < 18 * 2304) {
        int j = idx / 2304;
        int r = idx - j * 2304;           // r = c*9 + tap
        owt[r * 24 + j] = ow[idx];
    }
    if (idx < 147456) {
        int j    = idx & 7;
        int r    = idx >> 3;
        int lane = r & 63;  r >>= 6;
        int ct   = r & 1;   r >>= 1;
        int half = r & 1;   r >>= 1;
        int ks   = r & 1;   r >>= 1;
        int tap  = r % 9;
        int g    = r / 9;
        int c  = ks * 32 + (lane >> 4) * 8 + j;
        int co = half * 32 + ct * 16 + (lane & 15);
        float v = wt[(((g * CG_ + co) * CG_ + c) * 9) + tap];
        aW[idx] = __float2bfloat16(v);
    }
}

// ---------------------------------------------------------------------------
// offset conv: 576 blocks x 512 threads = 64 spatial x 8 wave-uniform
// c-chunks(32). Wave-uniform chunk -> weight reads become scalar broadcasts.
// ---------------------------------------------------------------------------
__global__ __launch_bounds__(512) void offset_conv_kernel(
    const float* __restrict__ x, const float* __restrict__ owt,
    const float* __restrict__ bias, float* __restrict__ off)
{
    int blk   = blockIdx.x;               // 0..575
    int b     = blk / 144;
    int sp    = (blk % 144) * 64 + (threadIdx.x & 63);
    int chunk = __builtin_amdgcn_readfirstlane(threadIdx.x >> 6); // 0..7
    int h     = sp / W_;
    int w     = sp - h * W_;

    float acc[18];
#pragma unroll
    for (int j = 0; j < 18; ++j) acc[j] = 0.f;

    const float* xb = x + b * (C_ * HW_);
    int c0 = chunk * 32;
#pragma unroll 2
    for (int c = c0; c < c0 + 32; ++c) {
        const float* xc = xb + c * HW_;
        const float* wr = owt + (c * 9) * 24;   // wave-uniform -> s_load
        float v[9];
#pragma unroll
        for (int ky = 0; ky < 3; ++ky) {
            int y = h + ky - 1;
#pragma unroll
            for (int kx = 0; kx < 3; ++kx) {
                int xx = w + kx - 1;
                float t = 0.f;
                if ((unsigned)y < H_ && (unsigned)xx < W_) t = xc[y * W_ + xx];
                v[ky * 3 + kx] = t;
            }
        }
#pragma unroll
        for (int tap = 0; tap < 9; ++tap) {
            const float* wtap = wr + tap * 24;
            float4 w0 = *(const float4*)(wtap + 0);
            float4 w1 = *(const float4*)(wtap + 4);
            float4 w2 = *(const float4*)(wtap + 8);
            float4 w3 = *(const float4*)(wtap + 12);
            float2 w4 = *(const float2*)(wtap + 16);
            float vv = v[tap];
            acc[0]  = fmaf(vv, w0.x, acc[0]);
            acc[1]  = fmaf(vv, w0.y, acc[1]);
            acc[2]  = fmaf(vv, w0.z, acc[2]);
            acc[3]  = fmaf(vv, w0.w, acc[3]);
            acc[4]  = fmaf(vv, w1.x, acc[4]);
            acc[5]  = fmaf(vv, w1.y, acc[5]);
            acc[6]  = fmaf(vv, w1.z, acc[6]);
            acc[7]  = fmaf(vv, w1.w, acc[7]);
            acc[8]  = fmaf(vv, w2.x, acc[8]);
            acc[9]  = fmaf(vv, w2.y, acc[9]);
            acc[10] = fmaf(vv, w2.z, acc[10]);
            acc[11] = fmaf(vv, w2.w, acc[11]);
            acc[12] = fmaf(vv, w3.x, acc[12]);
            acc[13] = fmaf(vv, w3.y, acc[13]);
            acc[14] = fmaf(vv, w3.z, acc[14]);
            acc[15] = fmaf(vv, w3.w, acc[15]);
            acc[16] = fmaf(vv, w4.x, acc[16]);
            acc[17] = fmaf(vv, w4.y, acc[17]);
        }
    }
    __shared__ float red[512 * 19];
#pragma unroll
    for (int j = 0; j < 18; ++j) red[threadIdx.x * 19 + j] = acc[j];
    __syncthreads();
    if (chunk == 0) {
        int sl = threadIdx.x & 63;
#pragma unroll
        for (int j = 0; j < 18; ++j) {
            float s = 0.f;
#pragma unroll
            for (int kc = 0; kc < 8; ++kc) s += red[(sl + kc * 64) * 19 + j];
            off[b * (18 * HW_) + j * HW_ + sp] = s + bias[j];
        }
    }
}

// ---------------------------------------------------------------------------
// deform conv via MFMA. Block = (b,g,h): out tile 64co x 96w, K = 576.
// 384 threads = 6 waves = (co-half 2) x (w-third 3); wave tile 32co x 32w.
// Per tap: bilinear-sample 64c x 96w -> LDS as bf16x2, granule-XOR swizzled
// ([w][8 granules of 8c], granule g stored at g^(w&7)) so both the packed
// writes and the ds_read_b128 B-fragments are bank-conflict-free with
// 128B row pitch. A-fragments pre-packed (prep) -> loaded straight from L2
// at tap start, latency hidden under the sampling phase.
// XCD swizzle retained from r2 (FETCH 966->24 MB).
// ---------------------------------------------------------------------------
__global__ __launch_bounds__(384) void deform_kernel(
    const float* __restrict__ x, const float* __restrict__ off,
    const __hip_bfloat16* __restrict__ aW, float* __restrict__ out)
{
    int blk = blockIdx.x;                 // 0..1535
    int xcd = blk & 7;
    int s   = blk >> 3;                   // 0..191
    int bg  = xcd * 2 + (s / H_);         // 0..15
    int h   = s % H_;
    int g   = bg & 3;
    int b   = bg >> 2;
    int t    = threadIdx.x;
    int lane = t & 63;
    int wave = __builtin_amdgcn_readfirstlane(t >> 6);  // 0..5
    int half   = wave & 1;                // co half (32)
    int wthird = wave >> 1;               // w third (32)

    // sampling mapping: thread = (q, tw) with fixed w = tw across taps
    int q  = t / 96;                      // 0..3 -> word-in-granule
    int tw = t - q * 96;                  // 0..95 -> w

    __shared__ __align__(16) __hip_bfloat162 sS[96 * 32];  // [w][32 words]

    const float* xp   = x + (b * C_ + g * CG_) * HW_;
    const float* offb = off + b * (18 * HW_) + h * W_;
    const __hip_bfloat16* aWg = aW + (g * 9) * 4096;

    f32x4 acc[2][2] = {};                 // [ct co16][wt w16]

    for (int k = 0; k < K_; ++k) {
        // A-fragments for this tap (consumed after the barrier; the long
        // sampling phase hides the L2 latency)
        bf16x8 afrag[2][2];               // [ks][ct]
        const __hip_bfloat16* at = aWg + k * 4096 + half * 1024 + lane * 8;
#pragma unroll
        for (int ks = 0; ks < 2; ++ks)
#pragma unroll
            for (int ct = 0; ct < 2; ++ct)
                afrag[ks][ct] = *(const bf16x8*)(at + ks * 2048 + ct * 512);

        __syncthreads();                  // prev tap's B-tile fully consumed

        // per-thread bilinear table for (k, w=tw)
        int ky = k / 3, kx = k - ky * 3;
        float dy = offb[(2 * k) * HW_ + tw];
        float dx = offb[(2 * k + 1) * HW_ + tw];
        float py = (float)(h + ky - 1) + dy;
        float px = (float)(tw + kx - 1) + dx;
        bool valid = (py > -1.f) && (py < (float)H_) &&
                     (px > -1.f) && (px < (float)W_);
        float y0f = floorf(py), x0f = floorf(px);
        float ly = py - y0f, lx = px - x0f;
        int y0 = (int)y0f, x0 = (int)x0f;
        int y1 = y0 + 1,  x1 = x0 + 1;
        bool y0ok = valid && (y0 >= 0) && (y0 < H_);
        bool y1ok = valid && (y1 >= 0) && (y1 < H_);
        bool x0ok = (x0 >= 0) && (x0 < W_);
        bool x1ok = (x1 >= 0) && (x1 < W_);
        int y0c = min(max(y0, 0), H_ - 1) * W_;
        int y1c = min(max(y1, 0), H_ - 1) * W_;
        int x0c = min(max(x0, 0), W_ - 1);
        int x1c = min(max(x1, 0), W_ - 1);
        float bw0 = (y0ok && x0ok) ? (1.f - ly) * (1.f - lx) : 0.f;
        float bw1 = (y0ok && x1ok) ? (1.f - ly) * lx : 0.f;
        float bw2 = (y1ok && x0ok) ? ly * (1.f - lx) : 0.f;
        float bw3 = (y1ok && x1ok) ? ly * lx : 0.f;
        int o0 = y0c + x0c, o1 = y0c + x1c, o2 = y1c + x0c, o3 = y1c + x1c;

        // sample c = 8i+2q, 8i+2q+1 for i=0..7; pack bf16x2; swizzled store
        int wmask = tw & 7;
        __hip_bfloat162* srow = sS + tw * 32 + q;
#pragma unroll
        for (int i = 0; i < 8; ++i) {
            const float* xc0 = xp + (8 * i + 2 * q) * HW_;
            const float* xc1 = xc0 + HW_;
            float v0 = bw0 * xc0[o0] + bw1 * xc0[o1] + bw2 * xc0[o2] + bw3 * xc0[o3];
            float v1 = bw0 * xc1[o0] + bw1 * xc1[o1] + bw2 * xc1[o2] + bw3 * xc1[o3];
            srow[((i ^ wmask) << 2)] = __float22bfloat162_rn(make_float2(v0, v1));
        }
        __syncthreads();                  // B-tile ready

#pragma unroll
        for (int ks = 0; ks < 2; ++ks) {
#pragma unroll
            for (int wt = 0; wt < 2; ++wt) {
                int wrow = wthird * 32 + wt * 16 + (lane & 15);
                int gq   = ks * 4 + (lane >> 4);
                bf16x8 bfrag = *(const bf16x8*)(sS + wrow * 32 + ((gq ^ (wrow & 7)) << 2));
                acc[0][wt] = __builtin_amdgcn_mfma_f32_16x16x32_bf16(
                                 afrag[ks][0], bfrag, acc[0][wt], 0, 0, 0);
                acc[1][wt] = __builtin_amdgcn_mfma_f32_16x16x32_bf16(
                                 afrag[ks][1], bfrag, acc[1][wt], 0, 0, 0);
            }
        }
    }

    // epilogue: C/D layout col=lane&15 (w), row=(lane>>4)*4+reg (co)
    float* ob = out + ((b * C_ + g * CG_ + half * 32) * HW_) + h * W_ + wthird * 32;
    int rbase = (lane >> 4) * 4;
    int ncol  = lane & 15;
#pragma unroll
    for (int ct = 0; ct < 2; ++ct)
#pragma unroll
        for (int wt = 0; wt < 2; ++wt)
#pragma unroll
            for (int r = 0; r < 4; ++r)
                __builtin_nontemporal_store(
                    acc[ct][wt][r],
                    ob + (ct * 16 + rbase + r) * HW_ + wt * 16 + ncol);
}

// ---------------------------------------------------------------------------
extern "C" void kernel_launch(void* const* d_in, const int* in_sizes, int n_in,
                              void* d_out, int out_size, void* d_ws, size_t ws_size,
                              hipStream_t stream) {
    const float* x    = (const float*)d_in[0];
    const float* ow   = (const float*)d_in[1];   // offset_w (18,256,3,3)
    const float* obi  = (const float*)d_in[2];   // offset_b (18,)
    const float* wt   = (const float*)d_in[3];   // weight   (256,64,3,3)

    // workspace layout: off fp32 (663552) | owt fp32 (55296) | aW bf16 (147456)
    float* off = (float*)d_ws;
    float* owt = off + (size_t)B_ * 18 * HW_;
    __hip_bfloat16* aW = (__hip_bfloat16*)(owt + 2304 * 24);

    prep_kernel<<<576, 256, 0, stream>>>(ow, wt, owt, aW);
    offset_conv_kernel<<<576, 512, 0, stream>>>(x, owt, obi, off);
    deform_kernel<<<B_ * G_ * H_, 384, 0, stream>>>(x, off, aW, (float*)d_out);
}

// Round 4
// 262.931 us; speedup vs baseline: 3.0046x; 1.8600x over previous
//
#include <hip/hip_runtime.h>
#include <hip/hip_bf16.h>
#include <math.h>

#define B_   4
#define C_   256
#define H_   96
#define W_   96
#define HW_  (H_ * W_)
#define G_   4
#define CG_  64
#define K_   9

typedef __bf16  bf16x8 __attribute__((ext_vector_type(8)));
typedef float   f32x4  __attribute__((ext_vector_type(4)));

// ---------------------------------------------------------------------------
// prep:
//  owt[(c*9+tap)*24 + j] = offset_w[j][c][tap]   (fp32, padded stride 24)
//  aW: deform weights as bf16 in MFMA A-fragment lane order:
//    c  = ks*32 + (lane>>4)*8 + j ;  co = half*32 + ct*16 + (lane&15)
// ---------------------------------------------------------------------------
__global__ __launch_bounds__(256) void prep_kernel(
    const float* __restrict__ ow, const float* __restrict__ wt,
    float* __restrict__ owt, __hip_bfloat16* __restrict__ aW)
{
    int idx = blockIdx.x * 256 + threadIdx.x;
    if (idx < 18 * 2304) {
        int j = idx / 2304;
        int r = idx - j * 2304;           // r = c*9 + tap
        owt[r * 24 + j] = ow[idx];
    }
    if (idx < 147456) {
        int j    = idx & 7;
        int r    = idx >> 3;
        int lane = r & 63;  r >>= 6;
        int ct   = r & 1;   r >>= 1;
        int half = r & 1;   r >>= 1;
        int ks   = r & 1;   r >>= 1;
        int tap  = r % 9;
        int g    = r / 9;
        int c  = ks * 32 + (lane >> 4) * 8 + j;
        int co = half * 32 + ct * 16 + (lane & 15);
        float v = wt[(((g * CG_ + co) * CG_ + c) * 9) + tap];
        aW[idx] = __float2bfloat16(v);
    }
}

// ---------------------------------------------------------------------------
// transpose x (NCHW fp32) -> xt (NHWC bf16): xt[((b*96+h)*96+w)*256 + c].
// Dense 16B-per-lane corner gathers in deform become possible.
// Block = (b,h); LDS tile [w][c] pitch 264 (bank-rotate, 16B-aligned rows).
// ---------------------------------------------------------------------------
__global__ __launch_bounds__(256) void transpose_kernel(
    const float* __restrict__ x, __hip_bfloat16* __restrict__ xt)
{
    int blk = blockIdx.x;                 // 0..383 = b*96 + h
    int b = blk / H_, h = blk - b * H_;
    int t = threadIdx.x;
    __shared__ __align__(16) __hip_bfloat16 tile[96 * 264];
    const float* xb = x + (size_t)b * C_ * HW_ + h * W_;
    for (int r = 0; r < 96; ++r) {
        int e = r * 256 + t;              // 0..24575
        int c = e / 96, w = e - c * 96;
        tile[w * 264 + c] = __float2bfloat16(xb[c * HW_ + w]);
    }
    __syncthreads();
    __hip_bfloat16* ob = xt + (size_t)(b * H_ + h) * W_ * C_;
#pragma unroll
    for (int i = 0; i < 12; ++i) {
        int sIdx = i * 256 + t;           // 0..3071
        int px = sIdx >> 5, seg = sIdx & 31;
        *(bf16x8*)(ob + px * 256 + seg * 8) =
            *(const bf16x8*)(&tile[px * 264 + seg * 8]);
    }
}

// ---------------------------------------------------------------------------
// offset conv (unchanged from r3): 576 blocks x 512 threads.
// ---------------------------------------------------------------------------
__global__ __launch_bounds__(512) void offset_conv_kernel(
    const float* __restrict__ x, const float* __restrict__ owt,
    const float* __restrict__ bias, float* __restrict__ off)
{
    int blk   = blockIdx.x;               // 0..575
    int b     = blk / 144;
    int sp    = (blk % 144) * 64 + (threadIdx.x & 63);
    int chunk = __builtin_amdgcn_readfirstlane(threadIdx.x >> 6); // 0..7
    int h     = sp / W_;
    int w     = sp - h * W_;

    float acc[18];
#pragma unroll
    for (int j = 0; j < 18; ++j) acc[j] = 0.f;

    const float* xb = x + b * (C_ * HW_);
    int c0 = chunk * 32;
#pragma unroll 2
    for (int c = c0; c < c0 + 32; ++c) {
        const float* xc = xb + c * HW_;
        const float* wr = owt + (c * 9) * 24;   // wave-uniform -> s_load
        float v[9];
#pragma unroll
        for (int ky = 0; ky < 3; ++ky) {
            int y = h + ky - 1;
#pragma unroll
            for (int kx = 0; kx < 3; ++kx) {
                int xx = w + kx - 1;
                float t = 0.f;
                if ((unsigned)y < H_ && (unsigned)xx < W_) t = xc[y * W_ + xx];
                v[ky * 3 + kx] = t;
            }
        }
#pragma unroll
        for (int tap = 0; tap < 9; ++tap) {
            const float* wtap = wr + tap * 24;
            float4 w0 = *(const float4*)(wtap + 0);
            float4 w1 = *(const float4*)(wtap + 4);
            float4 w2 = *(const float4*)(wtap + 8);
            float4 w3 = *(const float4*)(wtap + 12);
            float2 w4 = *(const float2*)(wtap + 16);
            float vv = v[tap];
            acc[0]  = fmaf(vv, w0.x, acc[0]);
            acc[1]  = fmaf(vv, w0.y, acc[1]);
            acc[2]  = fmaf(vv, w0.z, acc[2]);
            acc[3]  = fmaf(vv, w0.w, acc[3]);
            acc[4]  = fmaf(vv, w1.x, acc[4]);
            acc[5]  = fmaf(vv, w1.y, acc[5]);
            acc[6]  = fmaf(vv, w1.z, acc[6]);
            acc[7]  = fmaf(vv, w1.w, acc[7]);
            acc[8]  = fmaf(vv, w2.x, acc[8]);
            acc[9]  = fmaf(vv, w2.y, acc[9]);
            acc[10] = fmaf(vv, w2.z, acc[10]);
            acc[11] = fmaf(vv, w2.w, acc[11]);
            acc[12] = fmaf(vv, w3.x, acc[12]);
            acc[13] = fmaf(vv, w3.y, acc[13]);
            acc[14] = fmaf(vv, w3.z, acc[14]);
            acc[15] = fmaf(vv, w3.w, acc[15]);
            acc[16] = fmaf(vv, w4.x, acc[16]);
            acc[17] = fmaf(vv, w4.y, acc[17]);
        }
    }
    __shared__ float red[512 * 19];
#pragma unroll
    for (int j = 0; j < 18; ++j) red[threadIdx.x * 19 + j] = acc[j];
    __syncthreads();
    if (chunk == 0) {
        int sl = threadIdx.x & 63;
#pragma unroll
        for (int j = 0; j < 18; ++j) {
            float s = 0.f;
#pragma unroll
            for (int kc = 0; kc < 8; ++kc) s += red[(sl + kc * 64) * 19 + j];
            off[b * (18 * HW_) + j * HW_ + sp] = s + bias[j];
        }
    }
}

// ---------------------------------------------------------------------------
// deform conv via MFMA, NHWC bf16 gather. Block = (b,g,h), 384 thr = 6 waves.
// Sampling: thread = (w = it*48 + t>>3, c8 = (t&7)*8): 4 corner bf16x8 loads
// (16B dense each) -> fp32 bilinear -> bf16x8 -> LDS row [w][64c] pitch 144B.
// Double-buffered: 1 barrier/tap; sample(k+1) issues before mfma(k).
// ---------------------------------------------------------------------------
__global__ __launch_bounds__(384, 4) void deform_kernel(
    const __hip_bfloat16* __restrict__ xt, const float* __restrict__ off,
    const __hip_bfloat16* __restrict__ aW, float* __restrict__ out)
{
    int blk = blockIdx.x;                 // 0..1535
    int xcd = blk & 7;
    int s   = blk >> 3;                   // 0..191
    int bg  = xcd * 2 + (s / H_);         // 0..15
    int h   = s % H_;
    int g   = bg & 3;
    int b   = bg >> 2;
    int t    = threadIdx.x;
    int lane = t & 63;
    int wave = __builtin_amdgcn_readfirstlane(t >> 6);  // 0..5
    int half   = wave & 1;                // co half (32)
    int wthird = wave >> 1;               // w third (32)

    __shared__ __align__(16) __hip_bfloat16 sS[2][96 * 72]; // [w][64c+pad]

    const __hip_bfloat16* xb = xt + (size_t)b * HW_ * C_ + g * CG_;
    const float* offb = off + b * (18 * HW_) + h * W_;
    const __hip_bfloat16* aWg = aW + (g * 9) * 4096;

    int tw8 = t >> 3;                     // 0..47
    int j8  = (t & 7) * 8;                // c offset within group

    f32x4 acc[2][2] = {};                 // [ct co16][wt w16]

    auto sample = [&](int k, int p) {
        int ky = k / 3, kx = k - ky * 3;
#pragma unroll
        for (int it = 0; it < 2; ++it) {
            int w  = it * 48 + tw8;
            float dy = offb[(2 * k) * HW_ + w];
            float dx = offb[(2 * k + 1) * HW_ + w];
            float py = (float)(h + ky - 1) + dy;
            float px = (float)(w + kx - 1) + dx;
            bool valid = (py > -1.f) && (py < (float)H_) &&
                         (px > -1.f) && (px < (float)W_);
            float y0f = floorf(py), x0f = floorf(px);
            float ly = py - y0f, lx = px - x0f;
            int y0 = (int)y0f, x0 = (int)x0f;
            int y1 = y0 + 1,  x1 = x0 + 1;
            bool y0ok = valid && (y0 >= 0) && (y0 < H_);
            bool y1ok = valid && (y1 >= 0) && (y1 < H_);
            bool x0ok = (x0 >= 0) && (x0 < W_);
            bool x1ok = (x1 >= 0) && (x1 < W_);
            int y0c = min(max(y0, 0), H_ - 1);
            int y1c = min(max(y1, 0), H_ - 1);
            int x0c = min(max(x0, 0), W_ - 1);
            int x1c = min(max(x1, 0), W_ - 1);
            float bw00 = (y0ok && x0ok) ? (1.f - ly) * (1.f - lx) : 0.f;
            float bw01 = (y0ok && x1ok) ? (1.f - ly) * lx : 0.f;
            float bw10 = (y1ok && x0ok) ? ly * (1.f - lx) : 0.f;
            float bw11 = (y1ok && x1ok) ? ly * lx : 0.f;
            // 4 dense 16B corner loads (8 channels each)
            bf16x8 c00 = *(const bf16x8*)(xb + (y0c * W_ + x0c) * C_ + j8);
            bf16x8 c01 = *(const bf16x8*)(xb + (y0c * W_ + x1c) * C_ + j8);
            bf16x8 c10 = *(const bf16x8*)(xb + (y1c * W_ + x0c) * C_ + j8);
            bf16x8 c11 = *(const bf16x8*)(xb + (y1c * W_ + x1c) * C_ + j8);
            bf16x8 r;
#pragma unroll
            for (int e = 0; e < 8; ++e) {
                float v = bw00 * (float)c00[e] + bw01 * (float)c01[e]
                        + bw10 * (float)c10[e] + bw11 * (float)c11[e];
                r[e] = (__bf16)v;
            }
            *(bf16x8*)(&sS[p][w * 72 + j8]) = r;
        }
    };

    auto mmtap = [&](int k, int p) {
        bf16x8 afrag[2][2];               // [ks][ct]
        const __hip_bfloat16* at = aWg + k * 4096 + half * 1024 + lane * 8;
#pragma unroll
        for (int ks = 0; ks < 2; ++ks)
#pragma unroll
            for (int ct = 0; ct < 2; ++ct)
                afrag[ks][ct] = *(const bf16x8*)(at + ks * 2048 + ct * 512);
#pragma unroll
        for (int ks = 0; ks < 2; ++ks) {
#pragma unroll
            for (int wt = 0; wt < 2; ++wt) {
                int wrow = wthird * 32 + wt * 16 + (lane & 15);
                bf16x8 bfrag = *(const bf16x8*)(
                    &sS[p][wrow * 72 + ks * 32 + (lane >> 4) * 8]);
                acc[0][wt] = __builtin_amdgcn_mfma_f32_16x16x32_bf16(
                                 afrag[ks][0], bfrag, acc[0][wt], 0, 0, 0);
                acc[1][wt] = __builtin_amdgcn_mfma_f32_16x16x32_bf16(
                                 afrag[ks][1], bfrag, acc[1][wt], 0, 0, 0);
            }
        }
    };

    sample(0, 0);
    __syncthreads();
    for (int k = 0; k < K_; ++k) {
        if (k < K_ - 1) sample(k + 1, (k + 1) & 1);  // loads issue early
        mmtap(k, k & 1);
        __syncthreads();
    }

    // epilogue: C/D layout col=lane&15 (w), row=(lane>>4)*4+reg (co)
    float* ob = out + ((b * C_ + g * CG_ + half * 32) * HW_) + h * W_ + wthird * 32;
    int rbase = (lane >> 4) * 4;
    int ncol  = lane & 15;
#pragma unroll
    for (int ct = 0; ct < 2; ++ct)
#pragma unroll
        for (int wt = 0; wt < 2; ++wt)
#pragma unroll
            for (int r = 0; r < 4; ++r)
                __builtin_nontemporal_store(
                    acc[ct][wt][r],
                    ob + (ct * 16 + rbase + r) * HW_ + wt * 16 + ncol);
}

// ---------------------------------------------------------------------------
extern "C" void kernel_launch(void* const* d_in, const int* in_sizes, int n_in,
                              void* d_out, int out_size, void* d_ws, size_t ws_size,
                              hipStream_t stream) {
    const float* x    = (const float*)d_in[0];
    const float* ow   = (const float*)d_in[1];   // offset_w (18,256,3,3)
    const float* obi  = (const float*)d_in[2];   // offset_b (18,)
    const float* wt   = (const float*)d_in[3];   // weight   (256,64,3,3)

    // workspace: xt bf16 (9.44M) | off fp32 (663552) | owt fp32 (55296) | aW bf16
    __hip_bfloat16* xt = (__hip_bfloat16*)d_ws;              // 18,874,368 B
    float* off = (float*)(xt + (size_t)B_ * HW_ * C_);
    float* owt = off + (size_t)B_ * 18 * HW_;
    __hip_bfloat16* aW = (__hip_bfloat16*)(owt + 2304 * 24);

    prep_kernel<<<576, 256, 0, stream>>>(ow, wt, owt, aW);
    transpose_kernel<<<B_ * H_, 256, 0, stream>>>(x, xt);
    offset_conv_kernel<<<576, 512, 0, stream>>>(x, owt, obi, off);
    deform_kernel<<<B_ * G_ * H_, 384, 0, stream>>>(xt, off, aW, (float*)d_out);
}

// Round 5
// 194.348 us; speedup vs baseline: 4.0649x; 1.3529x over previous
//
#include <hip/hip_runtime.h>
#include <hip/hip_bf16.h>
#include <math.h>

#define B_   4
#define C_   256
#define H_   96
#define W_   96
#define HW_  (H_ * W_)
#define G_   4
#define CG_  64
#define K_   9
#define PW_  98                            // padded width/height (1-px halo)
#define PROW_ (PW_ * C_)                   // padded row pitch in elems

typedef __bf16  bf16x8 __attribute__((ext_vector_type(8)));
typedef float   f32x4  __attribute__((ext_vector_type(4)));

// ---------------------------------------------------------------------------
// prep:
//  aOW: offset-conv weights, MFMA A order, M padded 18->32:
//    idx = ((tap*8+ks)*2+mt)*512 + lane*8 + j
//    m = mt*16 + (lane&15) (out chan j, 0 if >=18); k = ks*32+(lane>>4)*8+j (c)
//  aW: deform weights bf16, MFMA A order (as r4):
//    c = ks*32+(lane>>4)*8+j ; co = half*32+ct*16+(lane&15)
// ---------------------------------------------------------------------------
__global__ __launch_bounds__(256) void prep_kernel(
    const float* __restrict__ ow, const float* __restrict__ wt,
    __hip_bfloat16* __restrict__ aOW, __hip_bfloat16* __restrict__ aW)
{
    int idx = blockIdx.x * 256 + threadIdx.x;
    if (idx < 73728) {
        int j    = idx & 7;
        int r    = idx >> 3;
        int lane = r & 63;  r >>= 6;
        int mt   = r & 1;   r >>= 1;
        int ks   = r & 7;   r >>= 3;
        int tap  = r;                     // 0..8
        int m = mt * 16 + (lane & 15);
        int c = ks * 32 + (lane >> 4) * 8 + j;
        float v = (m < 18) ? ow[(m * 256 + c) * 9 + tap] : 0.f;
        aOW[idx] = __float2bfloat16(v);
    }
    if (idx < 147456) {
        int j    = idx & 7;
        int r    = idx >> 3;
        int lane = r & 63;  r >>= 6;
        int ct   = r & 1;   r >>= 1;
        int half = r & 1;   r >>= 1;
        int ks   = r & 1;   r >>= 1;
        int tap  = r % 9;
        int g    = r / 9;
        int c  = ks * 32 + (lane >> 4) * 8 + j;
        int co = half * 32 + ct * 16 + (lane & 15);
        float v = wt[(((g * CG_ + co) * CG_ + c) * 9) + tap];
        aW[idx] = __float2bfloat16(v);
    }
}

// ---------------------------------------------------------------------------
// transpose x (NCHW fp32) -> xtp (padded NHWC bf16, [b][98][98][256], halo=0).
// Halo zeroing every launch (ws is re-poisoned 0xAA).
// ---------------------------------------------------------------------------
__global__ __launch_bounds__(256) void transpose_kernel(
    const float* __restrict__ x, __hip_bfloat16* __restrict__ xtp)
{
    int blk = blockIdx.x;                 // 0..383 = b*96 + h
    int b = blk / H_, h = blk - b * H_;
    int t = threadIdx.x;
    __shared__ __align__(16) __hip_bfloat16 tile[96 * 264];
    const float* xb = x + (size_t)b * C_ * HW_ + h * W_;
    for (int r = 0; r < 96; ++r) {
        int e = r * 256 + t;              // 0..24575
        int c = e / 96, w = e - c * 96;
        tile[w * 264 + c] = __float2bfloat16(xb[c * HW_ + w]);
    }
    __syncthreads();
    __hip_bfloat16* ob = xtp + ((size_t)(b * PW_ + h + 1) * PW_ + 1) * C_;
#pragma unroll
    for (int i = 0; i < 12; ++i) {
        int sIdx = i * 256 + t;           // 0..3071
        int px = sIdx >> 5, seg = sIdx & 31;
        *(bf16x8*)(ob + px * 256 + seg * 8) =
            *(const bf16x8*)(&tile[px * 264 + seg * 8]);
    }
    bf16x8 z = {};
    if (t < 64) {                         // column halos of this row
        int side = t >> 5, i = t & 31;
        *(bf16x8*)(xtp + ((size_t)(b * PW_ + h + 1) * PW_ + side * 97) * C_ + i * 8) = z;
    }
    if (h == 0 || h == 95) {              // top/bottom halo rows
        int row = (h == 0) ? 0 : 97;
        __hip_bfloat16* rb = xtp + (size_t)(b * PW_ + row) * PROW_;
#pragma unroll
        for (int i = 0; i < 13; ++i) {
            int idx = i * 256 + t;
            if (idx < 3136) *(bf16x8*)(rb + idx * 8) = z;
        }
    }
}

// ---------------------------------------------------------------------------
// offset conv via MFMA: out[18 pad 32][96w] per (b,h) block, K=2304 (9 taps x
// 8 k-slices of 32c). B-frags are dense bf16x8 loads straight from padded xt
// (halo makes OOB taps contribute 0) -- no LDS. 6 waves x 16-w tiles.
// Offsets stored as interleaved bf16 (dy,dx) pairs.
// ---------------------------------------------------------------------------
__global__ __launch_bounds__(384) void offset_conv_kernel(
    const __hip_bfloat16* __restrict__ xtp, const __hip_bfloat16* __restrict__ aOW,
    const float* __restrict__ bias, __hip_bfloat16* __restrict__ off2)
{
    int blk = blockIdx.x;                 // 0..383
    int xcd = blk & 7;
    int s   = blk >> 3;                   // 0..47
    int bh  = xcd * 48 + s;               // XCD-chunked: neighbors share rows
    int b   = bh / H_, h = bh % H_;
    int t = threadIdx.x, lane = t & 63;
    int nt = __builtin_amdgcn_readfirstlane(t >> 6);  // 0..5 -> w tile
    int w0 = nt * 16;
    int ml = lane & 15, kq = lane >> 4;

    f32x4 acc0 = {}, acc1 = {};
    const __hip_bfloat16* xb = xtp + (size_t)b * (PW_ * PROW_);
#pragma unroll
    for (int ky = 0; ky < 3; ++ky) {
#pragma unroll
        for (int kx = 0; kx < 3; ++kx) {
            int tap = ky * 3 + kx;
            const __hip_bfloat16* brow =
                xb + ((h + ky) * PW_ + (w0 + ml + kx)) * C_ + kq * 8;
            const __hip_bfloat16* arow = aOW + tap * 8192 + lane * 8;
#pragma unroll
            for (int ks = 0; ks < 8; ++ks) {
                bf16x8 bf = *(const bf16x8*)(brow + ks * 32);
                bf16x8 a0 = *(const bf16x8*)(arow + ks * 1024);
                bf16x8 a1 = *(const bf16x8*)(arow + ks * 1024 + 512);
                acc0 = __builtin_amdgcn_mfma_f32_16x16x32_bf16(a0, bf, acc0, 0, 0, 0);
                acc1 = __builtin_amdgcn_mfma_f32_16x16x32_bf16(a1, bf, acc1, 0, 0, 0);
            }
        }
    }
    // C/D: col=lane&15 -> w, row=kq*4+r -> out channel j
    int w = w0 + ml;
#pragma unroll
    for (int r = 0; r < 4; ++r) {
        int j0 = kq * 4 + r;
        off2[((size_t)(b * 9 + (j0 >> 1)) * HW_ + h * W_ + w) * 2 + (j0 & 1)] =
            __float2bfloat16(acc0[r] + bias[j0]);
        int j1 = 16 + kq * 4 + r;
        if (j1 < 18)
            off2[((size_t)(b * 9 + (j1 >> 1)) * HW_ + h * W_ + w) * 2 + (j1 & 1)] =
                __float2bfloat16(acc1[r] + bias[j1]);
    }
}

// ---------------------------------------------------------------------------
// deform conv via MFMA, padded-NHWC bf16 gather (as r4 + padded pitch, bf16
// offsets). Block = (b,g,h), 384 thr = 6 waves; double-buffered B-tile.
// ---------------------------------------------------------------------------
__global__ __launch_bounds__(384, 4) void deform_kernel(
    const __hip_bfloat16* __restrict__ xtp, const __hip_bfloat16* __restrict__ off2,
    const __hip_bfloat16* __restrict__ aW, float* __restrict__ out)
{
    int blk = blockIdx.x;                 // 0..1535
    int xcd = blk & 7;
    int s   = blk >> 3;                   // 0..191
    int bg  = xcd * 2 + (s / H_);         // 0..15
    int h   = s % H_;
    int g   = bg & 3;
    int b   = bg >> 2;
    int t    = threadIdx.x;
    int lane = t & 63;
    int wave = __builtin_amdgcn_readfirstlane(t >> 6);  // 0..5
    int half   = wave & 1;                // co half (32)
    int wthird = wave >> 1;               // w third (32)

    __shared__ __align__(16) __hip_bfloat16 sS[2][96 * 72]; // [w][64c+pad]

    const __hip_bfloat16* xb = xtp + ((size_t)b * (PW_ * PW_) + 99) * C_ + g * CG_;
    const __hip_bfloat162* offp =
        (const __hip_bfloat162*)off2 + (size_t)(b * 9) * HW_ + h * W_;
    const __hip_bfloat16* aWg = aW + (g * 9) * 4096;

    int tw8 = t >> 3;                     // 0..47
    int j8  = (t & 7) * 8;                // c offset within group

    f32x4 acc[2][2] = {};                 // [ct co16][wt w16]

    auto sample = [&](int k, int p) {
        int ky = k / 3, kx = k - ky * 3;
#pragma unroll
        for (int it = 0; it < 2; ++it) {
            int w  = it * 48 + tw8;
            __hip_bfloat162 pr = offp[k * HW_ + w];
            float dy = __bfloat162float(pr.x);
            float dx = __bfloat162float(pr.y);
            float py = (float)(h + ky - 1) + dy;
            float px = (float)(w + kx - 1) + dx;
            bool valid = (py > -1.f) && (py < (float)H_) &&
                         (px > -1.f) && (px < (float)W_);
            float y0f = floorf(py), x0f = floorf(px);
            float ly = py - y0f, lx = px - x0f;
            int y0 = (int)y0f, x0 = (int)x0f;
            int y1 = y0 + 1,  x1 = x0 + 1;
            bool y0ok = valid && (y0 >= 0) && (y0 < H_);
            bool y1ok = valid && (y1 >= 0) && (y1 < H_);
            bool x0ok = (x0 >= 0) && (x0 < W_);
            bool x1ok = (x1 >= 0) && (x1 < W_);
            int y0c = min(max(y0, 0), H_ - 1);
            int y1c = min(max(y1, 0), H_ - 1);
            int x0c = min(max(x0, 0), W_ - 1);
            int x1c = min(max(x1, 0), W_ - 1);
            float bw00 = (y0ok && x0ok) ? (1.f - ly) * (1.f - lx) : 0.f;
            float bw01 = (y0ok && x1ok) ? (1.f - ly) * lx : 0.f;
            float bw10 = (y1ok && x0ok) ? ly * (1.f - lx) : 0.f;
            float bw11 = (y1ok && x1ok) ? ly * lx : 0.f;
            // 4 dense 16B corner loads (8 channels each), padded pitch
            bf16x8 c00 = *(const bf16x8*)(xb + (y0c * PW_ + x0c) * C_ + j8);
            bf16x8 c01 = *(const bf16x8*)(xb + (y0c * PW_ + x1c) * C_ + j8);
            bf16x8 c10 = *(const bf16x8*)(xb + (y1c * PW_ + x0c) * C_ + j8);
            bf16x8 c11 = *(const bf16x8*)(xb + (y1c * PW_ + x1c) * C_ + j8);
            bf16x8 r;
#pragma unroll
            for (int e = 0; e < 8; ++e) {
                float v = bw00 * (float)c00[e] + bw01 * (float)c01[e]
                        + bw10 * (float)c10[e] + bw11 * (float)c11[e];
                r[e] = (__bf16)v;
            }
            *(bf16x8*)(&sS[p][w * 72 + j8]) = r;
        }
    };

    auto mmtap = [&](int k, int p) {
        bf16x8 afrag[2][2];               // [ks][ct]
        const __hip_bfloat16* at = aWg + k * 4096 + half * 1024 + lane * 8;
#pragma unroll
        for (int ks = 0; ks < 2; ++ks)
#pragma unroll
            for (int ct = 0; ct < 2; ++ct)
                afrag[ks][ct] = *(const bf16x8*)(at + ks * 2048 + ct * 512);
#pragma unroll
        for (int ks = 0; ks < 2; ++ks) {
#pragma unroll
            for (int wt = 0; wt < 2; ++wt) {
                int wrow = wthird * 32 + wt * 16 + (lane & 15);
                bf16x8 bfrag = *(const bf16x8*)(
                    &sS[p][wrow * 72 + ks * 32 + (lane >> 4) * 8]);
                acc[0][wt] = __builtin_amdgcn_mfma_f32_16x16x32_bf16(
                                 afrag[ks][0], bfrag, acc[0][wt], 0, 0, 0);
                acc[1][wt] = __builtin_amdgcn_mfma_f32_16x16x32_bf16(
                                 afrag[ks][1], bfrag, acc[1][wt], 0, 0, 0);
            }
        }
    };

    sample(0, 0);
    __syncthreads();
    for (int k = 0; k < K_; ++k) {
        if (k < K_ - 1) sample(k + 1, (k + 1) & 1);  // loads issue early
        mmtap(k, k & 1);
        __syncthreads();
    }

    // epilogue: C/D layout col=lane&15 (w), row=(lane>>4)*4+reg (co)
    float* ob = out + ((b * C_ + g * CG_ + half * 32) * HW_) + h * W_ + wthird * 32;
    int rbase = (lane >> 4) * 4;
    int ncol  = lane & 15;
#pragma unroll
    for (int ct = 0; ct < 2; ++ct)
#pragma unroll
        for (int wt = 0; wt < 2; ++wt)
#pragma unroll
            for (int r = 0; r < 4; ++r)
                __builtin_nontemporal_store(
                    acc[ct][wt][r],
                    ob + (ct * 16 + rbase + r) * HW_ + wt * 16 + ncol);
}

// ---------------------------------------------------------------------------
extern "C" void kernel_launch(void* const* d_in, const int* in_sizes, int n_in,
                              void* d_out, int out_size, void* d_ws, size_t ws_size,
                              hipStream_t stream) {
    const float* x    = (const float*)d_in[0];
    const float* ow   = (const float*)d_in[1];   // offset_w (18,256,3,3)
    const float* obi  = (const float*)d_in[2];   // offset_b (18,)
    const float* wt   = (const float*)d_in[3];   // weight   (256,64,3,3)

    // ws: xtp bf16 padded (19.67MB) | off2 bf16 (1.33MB) | aW (0.29MB) | aOW (0.15MB)
    __hip_bfloat16* xtp  = (__hip_bfloat16*)d_ws;
    __hip_bfloat16* off2 = xtp + (size_t)B_ * PW_ * PW_ * C_;
    __hip_bfloat16* aW   = off2 + (size_t)B_ * 9 * HW_ * 2;
    __hip_bfloat16* aOW  = aW + 147456;

    prep_kernel<<<576, 256, 0, stream>>>(ow, wt, aOW, aW);
    transpose_kernel<<<B_ * H_, 256, 0, stream>>>(x, xtp);
    offset_conv_kernel<<<B_ * H_, 384, 0, stream>>>(xtp, aOW, obi, off2);
    deform_kernel<<<B_ * G_ * H_, 384, 0, stream>>>(xtp, off2, aW, (float*)d_out);
}